// Round 4
// baseline (4604.923 us; speedup 1.0000x reference)
//
#include <hip/hip_runtime.h>
#include <math.h>

#define N 64
#define TRI ((N * (N + 1)) / 2)   // 2080
#define MAX_SWEEPS 20
#define TOL2 1e-7f                // rel off-diag^2: rho <= 3.2e-4 (fp32 noise
                                  // floor is ~3e-5; 1e-10 NEVER converged ->
                                  // every matrix ran all 20 sweeps in R3)
#define WS_PER_MAT (N * N + N)    // G (row-major) + weight vector, floats

// One-sided Jacobi sweeps. Thread t owns column t of G in g[].
// Column norms TRACKED (n_p' = n_p - tt*d, n_q' = n_q + tt*d), refreshed
// every sweep. Both lanes of a pair compute bit-identical d (same product
// set, same summation order) -> identical (c,s): rotations stay coherent.
__device__ __forceinline__ void jacobi_sweeps(float g[N]) {
    const int t = threadIdx.x & 63;
    for (int sw = 0; sw < MAX_SWEEPS; ++sw) {
        // refresh tracked norm (4-way ILP)
        float n0 = 0.f, n1 = 0.f, n2 = 0.f, n3 = 0.f;
        #pragma unroll
        for (int k = 0; k < N; k += 4) {
            n0 = fmaf(g[k],     g[k],     n0);
            n1 = fmaf(g[k + 1], g[k + 1], n1);
            n2 = fmaf(g[k + 2], g[k + 2], n2);
            n3 = fmaf(g[k + 3], g[k + 3], n3);
        }
        float na = (n0 + n1) + (n2 + n3);
        int bad = 0;
        for (int m = 1; m < N; ++m) {
            const int q = t ^ m;        // XOR tournament: disjoint pairs,
            float pt[N];                // all pairs once per sweep
            // partner column + dot, 4 independent fma chains (was the
            // latency bottleneck as a single 64-deep chain)
            float d0 = 0.f, d1 = 0.f, d2 = 0.f, d3 = 0.f;
            #pragma unroll
            for (int k = 0; k < N; k += 4) {
                pt[k]     = __shfl_xor(g[k],     m, 64);
                pt[k + 1] = __shfl_xor(g[k + 1], m, 64);
                pt[k + 2] = __shfl_xor(g[k + 2], m, 64);
                pt[k + 3] = __shfl_xor(g[k + 3], m, 64);
                d0 = fmaf(g[k],     pt[k],     d0);
                d1 = fmaf(g[k + 1], pt[k + 1], d1);
                d2 = fmaf(g[k + 2], pt[k + 2], d2);
                d3 = fmaf(g[k + 3], pt[k + 3], d3);
            }
            const float d = (d0 + d1) + (d2 + d3);
            const float nb = __shfl_xor(na, m, 64);   // partner tracked norm
            bad |= (d * d > TOL2 * na * nb);
            const bool lower = (t < q);     // lower index plays "p"
            const float nlo = lower ? na : nb;
            const float nhi = lower ? nb : na;
            float c = 1.f, s = 0.f, tt = 0.f;
            if (fabsf(d) > 1e-36f) {
                // zero (c g_p - s g_q)·(s g_p + c g_q): t^2 + 2 tau t - 1 = 0
                // inner root -> |theta| <= pi/4 (cyclic convergence)
                const float tau = (nhi - nlo) / (2.f * d);
                tt = copysignf(1.f / (fabsf(tau) + sqrtf(fmaf(tau, tau, 1.f))), tau);
                c = rsqrtf(fmaf(tt, tt, 1.f));   // 1e-7 rel err: re-corrected
                s = tt * c;                      // by later sweeps, << tol
            }
            const float se = lower ? -s : s;
            const float st = lower ? -tt : tt;
            na = fmaf(st, d, na);               // analytic norm update
            #pragma unroll
            for (int k = 0; k < N; ++k) g[k] = fmaf(se, pt[k], c * g[k]);
        }
        if (!__any(bad)) break;                 // full sweep below tol
    }
}

// Phase 1: sweeps only, zero LDS. launch_bounds(64,3): allow up to ~168 VGPR
// so pt[64] stays resident (VGPR=76 in R3 => compiler re-issued the 64
// shuffles in the update pass, doubling LDS-pipe traffic).
__global__ __launch_bounds__(64, 3)
void jacobi_kernel(const float* __restrict__ X, float* __restrict__ ws) {
    const int b = blockIdx.x;
    const int t = threadIdx.x;
    const float* __restrict__ Xb = X + (size_t)b * (N * N);
    float g[N];
    #pragma unroll
    for (int k = 0; k < N; ++k) g[k] = Xb[k * N + t];   // coalesced rows
    jacobi_sweeps(g);
    float* __restrict__ wb = ws + (size_t)b * WS_PER_MAT;
    float nown = 0.f;
    #pragma unroll
    for (int k = 0; k < N; ++k) {
        wb[k * N + t] = g[k];
        nown = fmaf(g[k], g[k], nown);
    }
    float sv = sqrtf(nown);
    sv = fminf(fmaxf(sv, 1e-4f), 1e4f);
    wb[N * N + t] = logf(sv) / fmaxf(nown, 1e-12f);     // w_k = log s / s^2
}

// Phase 2: logm[i][j] = sum_t w_t S[i][t] S[j][t], 4x4 register tile per
// thread, triu-only coalesced writes.
__global__ __launch_bounds__(256)
void outer_kernel(const float* __restrict__ ws, float* __restrict__ out) {
    __shared__ float S[N][N + 1];
    __shared__ float wv[N];
    const int b = blockIdx.x;
    const int tid = threadIdx.x;
    const float* __restrict__ wb = ws + (size_t)b * WS_PER_MAT;
    for (int idx = tid; idx < N * N; idx += 256)
        S[idx >> 6][idx & 63] = wb[idx];
    if (tid < N) wv[tid] = wb[N * N + tid];
    __syncthreads();
    const int tx = tid & 15, ty = tid >> 4;
    const int i0 = ty * 4, j0 = tx * 4;
    float acc[4][4];
    #pragma unroll
    for (int r = 0; r < 4; ++r)
        #pragma unroll
        for (int c_ = 0; c_ < 4; ++c_) acc[r][c_] = 0.f;
    #pragma unroll 8
    for (int t = 0; t < N; ++t) {
        const float w = wv[t];
        float si[4], sj[4];
        #pragma unroll
        for (int r = 0; r < 4; ++r) si[r] = w * S[i0 + r][t];
        #pragma unroll
        for (int c_ = 0; c_ < 4; ++c_) sj[c_] = S[j0 + c_][t];
        #pragma unroll
        for (int r = 0; r < 4; ++r)
            #pragma unroll
            for (int c_ = 0; c_ < 4; ++c_)
                acc[r][c_] = fmaf(si[r], sj[c_], acc[r][c_]);
    }
    float* __restrict__ ob = out + (size_t)b * TRI;
    #pragma unroll
    for (int r = 0; r < 4; ++r) {
        const int i = i0 + r;
        const int st = i * (2 * N + 1 - i) / 2;
        #pragma unroll
        for (int c_ = 0; c_ < 4; ++c_) {
            const int j = j0 + c_;
            if (j >= i) ob[st + (j - i)] = acc[r][c_];
        }
    }
}

// Fallback if ws_size too small: fused sweeps + LDS epilogue.
__global__ __launch_bounds__(64)
void fused_kernel(const float* __restrict__ X, float* __restrict__ out) {
    __shared__ float Gt[N][N + 1];
    __shared__ float w[N];
    const int b = blockIdx.x;
    const int t = threadIdx.x;
    const float* __restrict__ Xb = X + (size_t)b * (N * N);
    float g[N];
    #pragma unroll
    for (int k = 0; k < N; ++k) g[k] = Xb[k * N + t];
    jacobi_sweeps(g);
    float nown = 0.f;
    #pragma unroll
    for (int k = 0; k < N; ++k) {
        Gt[t][k] = g[k];
        nown = fmaf(g[k], g[k], nown);
    }
    float sv = sqrtf(nown);
    sv = fminf(fmaxf(sv, 1e-4f), 1e4f);
    w[t] = logf(sv) / fmaxf(nown, 1e-12f);
    __syncthreads();
    float wr[N];
    #pragma unroll
    for (int k = 0; k < N; ++k) wr[k] = w[k];
    float* __restrict__ ob = out + (size_t)b * TRI;
    int i = 0, base = 0;
    for (int e = t; e < TRI; e += N) {
        while (base + (N - i) <= e) { base += (N - i); ++i; }
        const int j = i + (e - base);
        float acc = 0.f;
        #pragma unroll
        for (int k = 0; k < N; ++k)
            acc = fmaf(wr[k] * Gt[k][i], Gt[k][j], acc);
        ob[e] = acc;
    }
}

extern "C" void kernel_launch(void* const* d_in, const int* in_sizes, int n_in,
                              void* d_out, int out_size, void* d_ws, size_t ws_size,
                              hipStream_t stream) {
    const float* x = (const float*)d_in[0];
    float* out = (float*)d_out;
    const int B = in_sizes[0] / (N * N);   // 8192
    const size_t need = (size_t)B * WS_PER_MAT * sizeof(float);  // ~136 MB
    if (ws_size >= need) {
        jacobi_kernel<<<dim3(B), dim3(64), 0, stream>>>(x, (float*)d_ws);
        outer_kernel<<<dim3(B), dim3(256), 0, stream>>>((const float*)d_ws, out);
    } else {
        fused_kernel<<<dim3(B), dim3(64), 0, stream>>>(x, out);
    }
}